// Round 11
// baseline (273.128 us; speedup 1.0000x reference)
//
#include <hip/hip_runtime.h>
#include <hip/hip_fp16.h>

#define B_ 256
#define N_ 192
#define D_ 512
#define E_ 1024
#define H_ 512
#define K_ 58
#define M_ (B_*K_)      // 14848 real rows
#define M2_ (B_*64)     // 16384 padded rows (64 per batch, rows 58-63 zero)

typedef _Float16 f16;
typedef unsigned int u32;
typedef _Float16 half8 __attribute__((ext_vector_type(8)));
typedef float floatx16 __attribute__((ext_vector_type(16)));

__device__ inline half8 cvt8(float4 f0, float4 f1) {
  half8 r;
  r[0]=(f16)f0.x; r[1]=(f16)f0.y; r[2]=(f16)f0.z; r[3]=(f16)f0.w;
  r[4]=(f16)f1.x; r[5]=(f16)f1.y; r[6]=(f16)f1.z; r[7]=(f16)f1.w;
  return r;
}

// async global->LDS, 16B/lane; LDS dest = wave-uniform base + lane*16
__device__ inline void gl_lds16(const f16* g, f16* l) {
  __builtin_amdgcn_global_load_lds((const __attribute__((address_space(1))) u32*)g,
                                   (__attribute__((address_space(3))) u32*)l, 16, 0, 0);
}

// Stage 128x32 f16 tile with XOR swizzle: LDS slot (r, c') holds global chunk
// c = c' ^ ((r>>1)&3).  Lane l covers row l>>2, slot c'=l&3, fetching global
// chunk (l&3)^((l>>3)&3).  Conflict-free (2-way max) on MFMA fragment reads.
__device__ inline void stage128(const f16* gbase, int gstride, f16* sT, int w, int lane) {
  int lrow  = lane >> 2;
  int chunk = (lane & 3) ^ ((lane >> 3) & 3);
  gl_lds16(gbase + (size_t)(w*16      + lrow)*gstride + chunk*8, &sT[(w*16)*32]);
  gl_lds16(gbase + (size_t)(64 + w*16 + lrow)*gstride + chunk*8, &sT[(64 + w*16)*32]);
}

// ---------- setup: weight cvt + topk + gather + L2norm + stats-zero ---------
__global__ void setup_kernel(const float* __restrict__ Wfc, const float* __restrict__ W2,
                             const float* __restrict__ W1, const float* __restrict__ attn,
                             const float* __restrict__ emb,
                             f16* __restrict__ Wcat, f16* __restrict__ W1_16,
                             f16* __restrict__ A16, float* __restrict__ csum) {
  __shared__ float sv[N_];
  __shared__ int sidx[K_];
  __shared__ int cnt;
  int blk = blockIdx.x, t = threadIdx.x;
  if (blk < 512) {                      // Wcat = [Wfc;W2]: 1024x1024 f16
    int idx = (blk*256 + t)*8;
    int e = idx >> 10, c = idx & 1023;
    const float* src = (c < 512) ? (Wfc + (size_t)e*512 + c)
                                 : (W2  + (size_t)e*512 + (c-512));
    half8 o = cvt8(((const float4*)src)[0], ((const float4*)src)[1]);
    *(uint4*)(Wcat + idx) = *(uint4*)&o;
  } else if (blk < 640) {               // W1_16: 512x512 f16
    int idx = ((blk-512)*256 + t)*8;
    const float* src = W1 + idx;
    half8 o = cvt8(((const float4*)src)[0], ((const float4*)src)[1]);
    *(uint4*)(W1_16 + idx) = *(uint4*)&o;
  } else if (blk < 896) {               // topk + gather + L2norm for batch b
    int b = blk - 640;
    if (t == 0) cnt = 0;
    if (t < N_) sv[t] = attn[(size_t)b*193*193 + 1 + t];
    __syncthreads();
    if (t < N_) {
      float v = sv[t]; int rank = 0;
      for (int j = 0; j < N_; ++j) {
        float vj = sv[j];
        rank += (vj > v) || (vj == v && j < t);   // lax.top_k stable tie-break
      }
      if (rank < K_) sidx[atomicAdd(&cnt, 1)] = t;  // slot order irrelevant (max/BN invariant)
    }
    __syncthreads();
    int w = t >> 6, lane = t & 63;
    for (int slot = w; slot < 64; slot += 4) {
      f16* dst = A16 + ((size_t)b*64 + slot)*1024 + lane*8;
      if (slot < K_) {
        const float* src = emb + ((size_t)b*N_ + sidx[slot])*D_ + lane*8;
        float4 v0 = ((const float4*)src)[0];
        float4 v1 = ((const float4*)src)[1];
        float s = v0.x*v0.x + v0.y*v0.y + v0.z*v0.z + v0.w*v0.w
                + v1.x*v1.x + v1.y*v1.y + v1.z*v1.z + v1.w*v1.w;
        #pragma unroll
        for (int off = 32; off > 0; off >>= 1) s += __shfl_xor(s, off);
        float inv = 1.0f / (sqrtf(s) + 1e-8f);
        half8 o;
        o[0]=(f16)(v0.x*inv); o[1]=(f16)(v0.y*inv); o[2]=(f16)(v0.z*inv); o[3]=(f16)(v0.w*inv);
        o[4]=(f16)(v1.x*inv); o[5]=(f16)(v1.y*inv); o[6]=(f16)(v1.z*inv); o[7]=(f16)(v1.w*inv);
        *(uint4*)dst = *(uint4*)&o;
      } else {
        uint4 z; z.x=0u; z.y=0u; z.z=0u; z.w=0u;
        *(uint4*)dst = z;   // pad rows zero
      }
    }
  } else {                              // zero csum(512)+css(512), contiguous
    float4 z; z.x=0.f; z.y=0.f; z.z=0.f; z.w=0.f;
    ((float4*)csum)[t] = z;
  }
}

// ---------- gemm1: A16[:,512:1024] = A16[:,0:512] @ W1_16^T + b1 + stats ----
// 128x128 tile, BK=32, dbuf LDS, 32x32x16 MFMA, XCD-swizzled grid (512 blocks).
__launch_bounds__(256, 2)
__global__ void gemm1_kernel(const f16* __restrict__ A16, const f16* __restrict__ W1_16,
                             const float* __restrict__ b1, f16* __restrict__ Aout,
                             float* __restrict__ csum, float* __restrict__ css) {
  __shared__ f16 sA[2][128*32];
  __shared__ f16 sB[2][128*32];
  __shared__ float sSum[4][64], sSS[4][64];
  int t = threadIdx.x;
  int g = blockIdx.x;                   // 512 blocks: xcd-swizzled
  int xcd = g & 7, rest = g >> 3;
  int n0 = (rest & 3) * 128;            // 4 n-tiles
  int m0 = (xcd + 8*(rest >> 2)) * 128; // same-m blocks same XCD
  int lane = t & 63, w = t >> 6;
  int l31 = lane & 31, khalf = lane >> 5, swz = (l31 >> 1) & 3;
  int rw = w & 1, cw = w >> 1;          // wave -> 64-row half x 64-col half
  floatx16 acc[2][2] = {};
  const f16* Ab = A16 + (size_t)m0*1024;       // left half (cols 0..511)
  const f16* Bb = W1_16 + (size_t)n0*512;
  stage128(Ab, 1024, sA[0], w, lane);
  stage128(Bb, 512,  sB[0], w, lane);
  __syncthreads();
  for (int it = 0; it < 16; ++it) {
    int cur = it & 1, nxt = cur ^ 1;
    if (it < 15) {
      stage128(Ab + (it+1)*32, 1024, sA[nxt], w, lane);
      stage128(Bb + (it+1)*32, 512,  sB[nxt], w, lane);
    }
    #pragma unroll
    for (int s = 0; s < 2; ++s) {       // two K=16 steps per 32-wide buffer
      int ko = ((s*2 + khalf) ^ swz) * 8;
      half8 a[2], bf[2];
      #pragma unroll
      for (int i = 0; i < 2; ++i) a[i]  = *(const half8*)&sA[cur][(rw*64 + i*32 + l31)*32 + ko];
      #pragma unroll
      for (int j = 0; j < 2; ++j) bf[j] = *(const half8*)&sB[cur][(cw*64 + j*32 + l31)*32 + ko];
      #pragma unroll
      for (int i = 0; i < 2; ++i)
        #pragma unroll
        for (int j = 0; j < 2; ++j)
          acc[i][j] = __builtin_amdgcn_mfma_f32_32x32x16_f16(a[i], bf[j], acc[i][j], 0, 0, 0);
    }
    __syncthreads();
  }
  // epilogue: write pre-BN h into A16 right half, masked column stats
  // C/D: col = l31, row = (reg&3) + 8*(reg>>2) + 4*khalf  (within 32x32 tile)
  #pragma unroll
  for (int jt = 0; jt < 2; ++jt) {
    int col = n0 + cw*64 + jt*32 + l31;
    float bias = b1[col];
    float s = 0.f, ss = 0.f;
    #pragma unroll
    for (int i = 0; i < 2; ++i) {
      #pragma unroll
      for (int rg = 0; rg < 16; ++rg) {
        int rib = i*32 + (rg&3) + 8*(rg>>2) + 4*khalf;   // row within batch (0..63)
        float x = acc[i][jt][rg] + bias;
        Aout[(size_t)(m0 + rw*64 + rib)*1024 + 512 + col] = (f16)x;
        if (i == 0 || rib < K_) { s += x; ss += x*x; }
      }
    }
    s  += __shfl_xor(s, 32);
    ss += __shfl_xor(ss, 32);
    if (lane < 32) { sSum[w][jt*32 + l31] = s; sSS[w][jt*32 + l31] = ss; }
  }
  __syncthreads();
  if (t < 128) {
    int c = t;                          // 128 cols in this block
    int w0 = 2*(c >> 6), ci = c & 63;   // waves rw=0/1 of this col-half
    atomicAdd(&csum[n0 + c], sSum[w0][ci] + sSum[w0+1][ci]);
    atomicAdd(&css[n0 + c],  sSS[w0][ci]  + sSS[w0+1][ci]);
  }
}

// ---------- fused: persistent-batch.  One block per batch; the 64x1024 A-row
// panel lives in 128 KB LDS (swizzled: row r slot s holds chunk s^(r&7); 16B
// chunks), staged ONCE: left half via global_load_lds (per-lane chunk permute),
// right half via regs + BN+relu + pad-zero.  Inner loop has NO barriers:
// B-fragments stream from global (Wcat L2-resident), A-fragments from LDS.
// Each wave owns 256 e-cols; max-epilogue is wave-local.
__launch_bounds__(256, 1)
__global__ void fused_kernel(const f16* __restrict__ A16, const f16* __restrict__ Wcat,
                             const float* __restrict__ csum, const float* __restrict__ css,
                             const float* __restrict__ gamma, const float* __restrict__ beta,
                             const float* __restrict__ bfc, const float* __restrict__ b2,
                             float* __restrict__ out) {
  extern __shared__ f16 sA[];           // 64*1024 f16 = 128 KB (dynamic)
  __shared__ float sSc[H_], sSh[H_];
  int t = threadIdx.x;
  int b = blockIdx.x;
  int lane = t & 63, w = t >> 6;
  int l31 = lane & 31, khalf = lane >> 5;
  // BN scale/shift from gemm1's global stats
  #pragma unroll
  for (int jj = 0; jj < 2; ++jj) {
    int j = t + jj*256;
    float mu  = csum[j] * (1.0f/M_);
    float var = css[j] * (1.0f/M_) - mu*mu;
    float sc  = gamma[j] * rsqrtf(var + 1e-5f);
    sSc[j] = sc;
    sSh[j] = beta[j] - mu*sc;
  }
  __syncthreads();                      // sSc/sSh ready (reg path reads them)
  const f16* Ab = A16 + (size_t)b*64*1024;
  // ---- stage left half (chunks 0..63 of each row) via global_load_lds ----
  for (int r = w; r < 64; r += 4) {
    int rx = r & 7;
    // wave-uniform LDS base row r; lane l -> slot l, fetches chunk l^rx
    gl_lds16(Ab + (size_t)r*1024 + ((lane ^ rx) * 8), &sA[r*1024]);
  }
  // ---- stage right half (chunks 64..127) via regs: BN+relu, pad rows zero --
  {
    int r  = t & 63;
    int rx = r & 7;
    int cb = 64 + (t >> 6) * 16;        // 16 chunks per thread
    bool padr = (r >= K_);
    const f16* hp = Ab + (size_t)r*1024;
    #pragma unroll
    for (int q = 0; q < 16; ++q) {
      int c = cb + q;
      uint4 hv4 = *(const uint4*)(hp + c*8);
      half8 hv = *(half8*)&hv4;
      int j0 = c*8 - 512;
      half8 o;
      #pragma unroll
      for (int i = 0; i < 8; ++i)
        o[i] = (f16)fmaxf((float)hv[i]*sSc[j0+i] + sSh[j0+i], 0.0f);
      uint4 ov = *(uint4*)&o;
      if (padr) { ov.x=0u; ov.y=0u; ov.z=0u; ov.w=0u; }
      *(uint4*)&sA[r*1024 + (c ^ rx)*8] = ov;
    }
  }
  __syncthreads();                      // panel complete (drains gl_lds too)
  // ---- 4 e-subtiles of 64 cols each; wave w owns cols [w*256, w*256+256) ---
  int rxl = l31 & 7;
  int aoff0 = l31*1024;                 // A row i=0 base (f16 units)
  int aoff1 = (32 + l31)*1024;          // A row i=1 base
  for (int st = 0; st < 4; ++st) {
    int colbase = w*256 + st*64;
    const f16* bp0 = Wcat + (size_t)(colbase      + l31)*1024 + khalf*8;
    const f16* bp1 = Wcat + (size_t)(colbase + 32 + l31)*1024 + khalf*8;
    floatx16 acc[2][2] = {};
    #pragma unroll 4
    for (int ks = 0; ks < 64; ++ks) {   // K = 64 steps of 16
      int kc = ks*2;                    // chunk pair base
      int so = ((kc + khalf) ^ rxl) * 8;
      half8 a0 = *(const half8*)&sA[aoff0 + so];
      half8 a1 = *(const half8*)&sA[aoff1 + so];
      half8 b0 = *(const half8*)(bp0 + kc*8);
      half8 b1v = *(const half8*)(bp1 + kc*8);
      acc[0][0] = __builtin_amdgcn_mfma_f32_32x32x16_f16(a0, b0,  acc[0][0], 0, 0, 0);
      acc[0][1] = __builtin_amdgcn_mfma_f32_32x32x16_f16(a0, b1v, acc[0][1], 0, 0, 0);
      acc[1][0] = __builtin_amdgcn_mfma_f32_32x32x16_f16(a1, b0,  acc[1][0], 0, 0, 0);
      acc[1][1] = __builtin_amdgcn_mfma_f32_32x32x16_f16(a1, b1v, acc[1][1], 0, 0, 0);
    }
    // epilogue: masked max over 58 real rows; wave-local, no LDS needed
    // C/D: col = l31, row = (rg&3) + 8*(rg>>2) + 4*khalf (+32 for i=1)
    #pragma unroll
    for (int j = 0; j < 2; ++j) {
      float mx = -3.0e38f;
      #pragma unroll
      for (int rg = 0; rg < 16; ++rg) mx = fmaxf(mx, acc[0][j][rg]);   // rows 0..31 all real
      #pragma unroll
      for (int rg = 0; rg < 16; ++rg) {
        int rib = 32 + (rg&3) + 8*(rg>>2) + 4*khalf;
        if (rib < K_) mx = fmaxf(mx, acc[1][j][rg]);
      }
      mx = fmaxf(mx, __shfl_xor(mx, 32));
      if (lane < 32) {
        int e = colbase + j*32 + l31;
        out[(size_t)b*E_ + e] = mx + bfc[e] + b2[e];
      }
    }
  }
}

extern "C" void kernel_launch(void* const* d_in, const int* in_sizes, int n_in,
                              void* d_out, int out_size, void* d_ws, size_t ws_size,
                              hipStream_t stream) {
  const float* emb   = (const float*)d_in[0];
  const float* attn  = (const float*)d_in[1];
  const float* Wfc   = (const float*)d_in[2];
  const float* bfc   = (const float*)d_in[3];
  const float* W1    = (const float*)d_in[4];
  const float* b1    = (const float*)d_in[5];
  const float* gamma = (const float*)d_in[6];
  const float* beta  = (const float*)d_in[7];
  const float* W2    = (const float*)d_in[8];
  const float* b2    = (const float*)d_in[9];
  float* out = (float*)d_out;

  char* ws = (char*)d_ws;
  f16*   A16   = (f16*)(ws);                    // 16384*1024*2 = 33,554,432
  f16*   Wcat  = (f16*)(ws + 33554432);         // 1024*1024*2  =  2,097,152
  f16*   W1_16 = (f16*)(ws + 35651584);         //  512*512*2   =    524,288
  float* csum  = (float*)(ws + 36175872);       // 2048
  float* css   = (float*)(ws + 36177920);       // 2048 (contiguous after csum)

  setup_kernel<<<897, 256, 0, stream>>>(Wfc, W2, W1, attn, emb, Wcat, W1_16, A16, csum);
  gemm1_kernel<<<512, 256, 0, stream>>>(A16, W1_16, b1, A16, csum, css);
  fused_kernel<<<256, 256, 131072, stream>>>(A16, Wcat, csum, css, gamma, beta, bfc, b2, out);
}